// Round 1
// baseline (155.605 us; speedup 1.0000x reference)
//
#include <hip/hip_runtime.h>
#include <math.h>

// out = softmax((Q .* K^T) / 64 .* V, axis=1)
// Q: [8192,4096] f32 row-major; K: [4096,8192] f32 row-major (we need K[j][i]);
// V: [8192,4096]; O: [8192,4096].
//
// One block = 16 rows, one wave per row (1024 thr). Whole row lives in regs
// (float4 x[16] = 64 VGPR). K columns are gathered coalesced (lanes across i)
// and transposed through a padded LDS tile. Single pass over HBM: 512 MiB.

static constexpr int NROW = 8192;
static constexpr int D    = 4096;
static constexpr int RPB  = 16;          // rows per block == waves per block
static constexpr int TJ   = 256;         // columns per K tile
static constexpr int NT   = D / TJ;      // 16 tiles
static constexpr int LSTR = TJ + 4;      // 260 floats: pad keeps banks spread

__global__ __launch_bounds__(1024, 4)
void sdp_softmax_kernel(const float* __restrict__ Q,
                        const float* __restrict__ K,
                        const float* __restrict__ V,
                        float* __restrict__ O)
{
    __shared__ float ldsK[RPB * LSTR];

    const int tid  = threadIdx.x;
    const int wv   = tid >> 6;           // wave id = local row
    const int lane = tid & 63;

    // XCD-chunked swizzle: blocks 0..63 -> XCD0, etc. (512 % 8 == 0, bijective)
    const int nwg = gridDim.x;
    const int cpx = nwg >> 3;
    const int hb  = blockIdx.x;
    const int lb  = (hb & 7) * cpx + (hb >> 3);

    const int row0 = lb * RPB;
    const int r    = row0 + wv;

    const float* qrow = Q + (size_t)r * D;
    const float* vrow = V + (size_t)r * D;
    float*       orow = O + (size_t)r * D;

    // K staging: thread t loads 4 consecutive j (rows of K), fixed i = row0+il.
    // Per wave: 4 segments of 16 consecutive floats (64B) -> fully coalesced.
    const int il = tid & 15;             // which of the block's 16 rows (i)
    const int jg = tid >> 4;             // 0..63 -> j group of 4
    const float* kbase = K + (size_t)(4 * jg) * NROW + (size_t)row0 + il;

    // ---- prefetch tile 0 ----
    float ka = kbase[0];
    float kb = kbase[(size_t)NROW];
    float kc = kbase[2 * (size_t)NROW];
    float kd = kbase[3 * (size_t)NROW];
    float4 qv = *(const float4*)(qrow + 4 * lane);
    float4 vv = *(const float4*)(vrow + 4 * lane);

    float4 x[NT];
    float4 mx = make_float4(-INFINITY, -INFINITY, -INFINITY, -INFINITY);

    #pragma unroll
    for (int kt = 0; kt < NT; ++kt) {
        __syncthreads();   // previous tile's readers are done
        *(float4*)&ldsK[il * LSTR + 4 * jg] = make_float4(ka, kb, kc, kd);
        __syncthreads();   // tile staged

        float4 qc = qv, vc = vv;
        if (kt + 1 < NT) { // prefetch next tile while we compute this one
            const float* p = kbase + (size_t)(kt + 1) * TJ * NROW;
            ka = p[0];
            kb = p[(size_t)NROW];
            kc = p[2 * (size_t)NROW];
            kd = p[3 * (size_t)NROW];
            qv = *(const float4*)(qrow + (kt + 1) * TJ + 4 * lane);
            vv = *(const float4*)(vrow + (kt + 1) * TJ + 4 * lane);
        }

        // wave wv reads ldsK[wv][4*lane .. +3] = K[j0+4*lane+s][row0+wv]
        const float4 kf = *(const float4*)&ldsK[wv * LSTR + 4 * lane];
        float4 xx;
        xx.x = ((qc.x * kf.x) * 0.015625f) * vc.x;  // /64 is exact (pow2)
        xx.y = ((qc.y * kf.y) * 0.015625f) * vc.y;
        xx.z = ((qc.z * kf.z) * 0.015625f) * vc.z;
        xx.w = ((qc.w * kf.w) * 0.015625f) * vc.w;
        x[kt] = xx;
        mx.x = fmaxf(mx.x, xx.x);
        mx.y = fmaxf(mx.y, xx.y);
        mx.z = fmaxf(mx.z, xx.z);
        mx.w = fmaxf(mx.w, xx.w);
    }

    // row max: horizontal then wave-wide (row == wave, no cross-wave needed)
    float m = fmaxf(fmaxf(mx.x, mx.y), fmaxf(mx.z, mx.w));
    #pragma unroll
    for (int i = 1; i < 64; i <<= 1)
        m = fmaxf(m, __shfl_xor(m, i, 64));

    float s = 0.0f;
    #pragma unroll
    for (int kt = 0; kt < NT; ++kt) {
        float4 xx = x[kt];
        xx.x = __expf(xx.x - m);
        xx.y = __expf(xx.y - m);
        xx.z = __expf(xx.z - m);
        xx.w = __expf(xx.w - m);
        x[kt] = xx;
        s += (xx.x + xx.y) + (xx.z + xx.w);
    }
    #pragma unroll
    for (int i = 1; i < 64; i <<= 1)
        s += __shfl_xor(s, i, 64);

    const float inv = 1.0f / s;
    #pragma unroll
    for (int kt = 0; kt < NT; ++kt) {
        float4 xx = x[kt];
        xx.x *= inv; xx.y *= inv; xx.z *= inv; xx.w *= inv;
        *(float4*)(orow + (size_t)kt * TJ + 4 * lane) = xx;
    }
}

extern "C" void kernel_launch(void* const* d_in, const int* in_sizes, int n_in,
                              void* d_out, int out_size, void* d_ws, size_t ws_size,
                              hipStream_t stream) {
    const float* Q = (const float*)d_in[0];
    const float* K = (const float*)d_in[1];
    const float* V = (const float*)d_in[2];
    float* O = (float*)d_out;

    dim3 grid(NROW / RPB);   // 512 blocks
    dim3 block(1024);        // 16 waves
    sdp_softmax_kernel<<<grid, block, 0, stream>>>(Q, K, V, O);
}